// Round 15
// baseline (382.954 us; speedup 1.0000x reference)
//
#include <hip/hip_runtime.h>
#include <cstdint>
#include <cstddef>

#define N_NODES 10000
#define M_PAD   10112            // 79 * 128
#define N_EDGES 160000
#define ETOT    (N_EDGES + N_NODES)   // with self-loops
#define F_INDIM 300
#define K1PAD   320              // F_INDIM padded to mult of 32
#define HEADS   4
#define DH      256
#define C1      (HEADS * DH)     // 1024
#define NCLS    6
#define BN_EPS  1e-5f

typedef _Float16 half8 __attribute__((ext_vector_type(8)));
typedef _Float16 half4 __attribute__((ext_vector_type(4)));
typedef float f32x4 __attribute__((ext_vector_type(4)));

__device__ __forceinline__ void gld_lds16(const void* g, void* s) {
  __builtin_amdgcn_global_load_lds(
      (const __attribute__((address_space(1))) void*)g,
      (__attribute__((address_space(3))) void*)s, 16, 0, 0);
}

// ---------------------------------------------------------------------------
// fp16 MFMA GEMM: C[M,Nn] = A[M,K]fp16 @ B[Nn,K]fp16^T (NT), fp16 out.
// 128x128 tile, BK=32, 256 threads = 4 waves (2x2), 4x4 16x16x32 frags/wave.
// ---------------------------------------------------------------------------
__global__ __launch_bounds__(256) void k_mfma_gemm(
    const _Float16* __restrict__ A, const _Float16* __restrict__ B,
    _Float16* __restrict__ Ch, int M, int Nn, int K) {
  __shared__ __align__(16) _Float16 sA[128 * 32];
  __shared__ __align__(16) _Float16 sB[128 * 32];
  const int tid = threadIdx.x;
  const int lane = tid & 63, w = tid >> 6;
  const int wm = w >> 1, wn = w & 1;
  const int row0 = blockIdx.y * 128, col0 = blockIdx.x * 128;

  const int r_loc = lane >> 2;       // 0..15
  const int j8 = (lane & 3) * 8;     // half offset within BK=32
  const _Float16* gA = A + (size_t)(row0 + w * 32 + r_loc) * K + j8;
  const _Float16* gB = B + (size_t)(col0 + w * 32 + r_loc) * K + j8;
  _Float16* sAw = sA + (w * 32) * 32;
  _Float16* sBw = sB + (w * 32) * 32;

  const int fr = lane & 15, kb = lane >> 4;
  const _Float16* pA = sA + ((size_t)(wm * 64 + fr) * 32 + kb * 8);
  const _Float16* pB = sB + ((size_t)(wn * 64 + fr) * 32 + kb * 8);

  f32x4 acc[4][4] = {};
  const int KT = K / 32;

  {
    gld_lds16(gA, sAw);
    gld_lds16(gA + (size_t)16 * K, sAw + 16 * 32);
    gld_lds16(gB, sBw);
    gld_lds16(gB + (size_t)16 * K, sBw + 16 * 32);
  }
  for (int kt = 0; kt < KT; ++kt) {
    __syncthreads();
    half8 af[4], bf[4];
#pragma unroll
    for (int i = 0; i < 4; ++i) af[i] = *(const half8*)(pA + i * 16 * 32);
#pragma unroll
    for (int j = 0; j < 4; ++j) bf[j] = *(const half8*)(pB + j * 16 * 32);
    __syncthreads();
    if (kt + 1 < KT) {
      const _Float16* ga = gA + (size_t)(kt + 1) * 32;
      const _Float16* gb = gB + (size_t)(kt + 1) * 32;
      gld_lds16(ga, sAw);
      gld_lds16(ga + (size_t)16 * K, sAw + 16 * 32);
      gld_lds16(gb, sBw);
      gld_lds16(gb + (size_t)16 * K, sBw + 16 * 32);
    }
#pragma unroll
    for (int i = 0; i < 4; ++i)
#pragma unroll
      for (int j = 0; j < 4; ++j)
        acc[i][j] =
            __builtin_amdgcn_mfma_f32_16x16x32_f16(af[i], bf[j], acc[i][j], 0, 0, 0);
  }

  // C/D layout: col = lane&15, row = (lane>>4)*4 + reg
  const int orow = row0 + wm * 64 + kb * 4;
  const int ocol = col0 + wn * 64 + fr;
#pragma unroll
  for (int i = 0; i < 4; ++i) {
#pragma unroll
    for (int r = 0; r < 4; ++r) {
      const int rr = orow + i * 16 + r;
      if (rr >= M) continue;
#pragma unroll
      for (int j = 0; j < 4; ++j)
        Ch[(size_t)rr * Nn + ocol + j * 16] = (_Float16)acc[i][j][r];
    }
  }
}

// ---------------------------------------------------------------------------
// Fused MLP head: fc1 MFMA GEMM (bias+ReLU) -> LDS -> in-block fc2 (6 cols).
// ---------------------------------------------------------------------------
__global__ __launch_bounds__(256) void k_fc12(
    const _Float16* __restrict__ A, const _Float16* __restrict__ B,
    const float* __restrict__ b1f, const float* __restrict__ W2,
    const float* __restrict__ b2f, float* __restrict__ out) {
  __shared__ __align__(16) _Float16 sA[128 * 32];
  __shared__ __align__(16) _Float16 sB[128 * 32];
  __shared__ _Float16 sy[128][133];
  const int tid = threadIdx.x;
  const int lane = tid & 63, w = tid >> 6;
  const int wm = w >> 1, wn = w & 1;
  const int row0 = blockIdx.x * 128;
  const int K = DH;  // 256

  const int r_loc = lane >> 2;
  const int j8 = (lane & 3) * 8;
  const _Float16* gA = A + (size_t)(row0 + w * 32 + r_loc) * K + j8;
  const _Float16* gB = B + (size_t)(w * 32 + r_loc) * K + j8;
  _Float16* sAw = sA + (w * 32) * 32;
  _Float16* sBw = sB + (w * 32) * 32;

  const int fr = lane & 15, kb = lane >> 4;
  const _Float16* pA = sA + ((size_t)(wm * 64 + fr) * 32 + kb * 8);
  const _Float16* pB = sB + ((size_t)(wn * 64 + fr) * 32 + kb * 8);

  f32x4 acc[4][4] = {};
  const int KT = K / 32;  // 8
  {
    gld_lds16(gA, sAw);
    gld_lds16(gA + (size_t)16 * K, sAw + 16 * 32);
    gld_lds16(gB, sBw);
    gld_lds16(gB + (size_t)16 * K, sBw + 16 * 32);
  }
  for (int kt = 0; kt < KT; ++kt) {
    __syncthreads();
    half8 af[4], bf[4];
#pragma unroll
    for (int i = 0; i < 4; ++i) af[i] = *(const half8*)(pA + i * 16 * 32);
#pragma unroll
    for (int j = 0; j < 4; ++j) bf[j] = *(const half8*)(pB + j * 16 * 32);
    __syncthreads();
    if (kt + 1 < KT) {
      const _Float16* ga = gA + (size_t)(kt + 1) * 32;
      const _Float16* gb = gB + (size_t)(kt + 1) * 32;
      gld_lds16(ga, sAw);
      gld_lds16(ga + (size_t)16 * K, sAw + 16 * 32);
      gld_lds16(gb, sBw);
      gld_lds16(gb + (size_t)16 * K, sBw + 16 * 32);
    }
#pragma unroll
    for (int i = 0; i < 4; ++i)
#pragma unroll
      for (int j = 0; j < 4; ++j)
        acc[i][j] =
            __builtin_amdgcn_mfma_f32_16x16x32_f16(af[i], bf[j], acc[i][j], 0, 0, 0);
  }
  const int lrow = wm * 64 + kb * 4;
  const int lcol = wn * 64 + fr;
#pragma unroll
  for (int i = 0; i < 4; ++i)
#pragma unroll
    for (int r = 0; r < 4; ++r)
#pragma unroll
      for (int j = 0; j < 4; ++j) {
        float v = acc[i][j][r] + b1f[lcol + j * 16];
        sy[lrow + i * 16 + r][lcol + j * 16] = (_Float16)(v > 0.f ? v : 0.f);
      }
  __syncthreads();
#pragma unroll
  for (int q = 0; q < 3; ++q) {
    const int idx = tid * 3 + q;
    const int n = idx / NCLS, c = idx % NCLS;
    if (row0 + n < N_NODES) {
      float s = b2f[c];
      const float* w2 = W2 + c * 128;
#pragma unroll 8
      for (int k = 0; k < 128; ++k) s += (float)sy[n][k] * w2[k];
      out[(size_t)(row0 + n) * NCLS + c] = s;
    }
  }
}

// ---------------------------------------------------------------------------
// Mega-cvt: all fp32->fp16 conversions in ONE launch.
// ---------------------------------------------------------------------------
__device__ __forceinline__ void cvt_pair(const float* __restrict__ in,
                                         _Float16* __restrict__ out, int i,
                                         int K, int Kp) {
  const int kp2 = Kp >> 1;
  const int r = i / kp2, c2 = (i % kp2) * 2;
  const float vx = (c2 < K) ? in[(size_t)r * K + c2] : 0.f;
  const float vy = (c2 + 1 < K) ? in[(size_t)r * K + c2 + 1] : 0.f;
  out[(size_t)r * Kp + c2] = (_Float16)vx;
  out[(size_t)r * Kp + c2 + 1] = (_Float16)vy;
}

#define CV_S0 (N_NODES * (K1PAD / 2))
#define CV_S1 (C1 * (K1PAD / 2))
#define CV_S2 (C1 * (C1 / 2))
#define CV_S3 (DH * (C1 / 2))
#define CV_S4 (128 * (DH / 2))
#define CV_TOT (CV_S0 + CV_S1 + CV_S2 + CV_S3 + CV_S4)

__global__ __launch_bounds__(256) void k_cvt_all(
    const float* __restrict__ x, const float* __restrict__ W1,
    const float* __restrict__ W2, const float* __restrict__ W3,
    const float* __restrict__ fcW, _Float16* __restrict__ xh,
    _Float16* __restrict__ w1h, _Float16* __restrict__ w2h,
    _Float16* __restrict__ w3h, _Float16* __restrict__ fwh) {
  int i = blockIdx.x * 256 + threadIdx.x;
  if (i < CV_S0) { cvt_pair(x, xh, i, F_INDIM, K1PAD); return; }
  i -= CV_S0;
  if (i < CV_S1) { cvt_pair(W1, w1h, i, F_INDIM, K1PAD); return; }
  i -= CV_S1;
  if (i < CV_S2) { cvt_pair(W2, w2h, i, C1, C1); return; }
  i -= CV_S2;
  if (i < CV_S3) { cvt_pair(W3, w3h, i, C1, C1); return; }
  i -= CV_S3;
  if (i < CV_S4) { cvt_pair(fcW, fwh, i, DH, DH); return; }
}

// ---------------------------------------------------------------------------
// Fold bias+BN for BOTH layers: A/B[0..1024) = layer1, [1024..2048) = layer2.
// ---------------------------------------------------------------------------
__global__ __launch_bounds__(256) void k_bnp2(
    const float* __restrict__ b1, const float* __restrict__ g1,
    const float* __restrict__ be1, const float* __restrict__ m1,
    const float* __restrict__ v1, const float* __restrict__ b2,
    const float* __restrict__ g2, const float* __restrict__ be2,
    const float* __restrict__ m2, const float* __restrict__ v2,
    float* __restrict__ A, float* __restrict__ B) {
  const int c = blockIdx.x * 256 + threadIdx.x;
  if (c >= 2 * C1) return;
  if (c < C1) {
    const float rs = rsqrtf(v1[c] + BN_EPS) * g1[c];
    A[c] = rs;
    B[c] = (b1[c] - m1[c]) * rs + be1[c];
  } else {
    const int d = c - C1;
    const float rs = rsqrtf(v2[d] + BN_EPS) * g2[d];
    A[c] = rs;
    B[c] = (b2[d] - m2[d]) * rs + be2[d];
  }
}

// ---------------------------------------------------------------------------
// alpha_s[n,h] = <h[n,h,:], a_src[h,:]> from fp16 h. Block = HH*64.
// ---------------------------------------------------------------------------
template <int HH>
__global__ __launch_bounds__(HH * 64) void k_alpha(
    const _Float16* __restrict__ h, const float* __restrict__ a_src,
    const float* __restrict__ a_dst, float* __restrict__ as_,
    float* __restrict__ ad_) {
  const int n = blockIdx.x;
  const int tid = threadIdx.x;
  const int head = tid >> 6;
  const int lane = tid & 63;
  const half4 hv = *(const half4*)(h + (size_t)n * HH * DH + head * DH + lane * 4);
  const float4 sv = *(reinterpret_cast<const float4*>(a_src + head * DH) + lane);
  const float4 dv = *(reinterpret_cast<const float4*>(a_dst + head * DH) + lane);
  const float h0 = (float)hv[0], h1 = (float)hv[1], h2 = (float)hv[2],
              h3 = (float)hv[3];
  float s1 = h0 * sv.x + h1 * sv.y + h2 * sv.z + h3 * sv.w;
  float s2 = h0 * dv.x + h1 * dv.y + h2 * dv.z + h3 * dv.w;
#pragma unroll
  for (int off = 32; off > 0; off >>= 1) {
    s1 += __shfl_down(s1, off);
    s2 += __shfl_down(s2, off);
  }
  if (lane == 0) {
    as_[n * HH + head] = s1;
    ad_[n * HH + head] = s2;
  }
}

// ---------------------------------------------------------------------------
// CSR build (cnt1 for count, cnt2 for fill -> both zeroed by one memset)
// ---------------------------------------------------------------------------
__global__ __launch_bounds__(256) void k_count(const int* __restrict__ ei,
                                               int* __restrict__ cnt) {
  const int e = blockIdx.x * 256 + threadIdx.x;
  if (e >= ETOT) return;
  const int t = (e < N_EDGES) ? ei[N_EDGES + e] : (e - N_EDGES);
  atomicAdd(&cnt[t], 1);
}

__global__ __launch_bounds__(256) void k_scan(const int* __restrict__ cnt,
                                              int* __restrict__ rowptr) {
  __shared__ int part[256];
  const int tid = threadIdx.x;
  const int chunk = (N_NODES + 255) / 256;  // 40
  const int b = tid * chunk;
  int sum = 0;
  for (int i = 0; i < chunk; i++) {
    const int idx = b + i;
    if (idx < N_NODES) sum += cnt[idx];
  }
  part[tid] = sum;
  __syncthreads();
  for (int off = 1; off < 256; off <<= 1) {
    int t2 = (tid >= off) ? part[tid - off] : 0;
    __syncthreads();
    part[tid] += t2;
    __syncthreads();
  }
  int run = part[tid] - sum;
  for (int i = 0; i < chunk; i++) {
    const int idx = b + i;
    if (idx < N_NODES) {
      rowptr[idx] = run;
      run += cnt[idx];
    }
  }
  if (tid == 255) rowptr[N_NODES] = part[255];
}

__global__ __launch_bounds__(256) void k_fill(
    const int* __restrict__ ei, const int* __restrict__ rowptr,
    int* __restrict__ fill, int* __restrict__ csr_src) {
  const int e = blockIdx.x * 256 + threadIdx.x;
  if (e >= ETOT) return;
  int s, t;
  if (e < N_EDGES) { s = ei[e]; t = ei[N_EDGES + e]; }
  else             { s = t = e - N_EDGES; }
  const int pos = rowptr[t] + atomicAdd(&fill[t], 1);
  csr_src[pos] = s;
}

// ---------------------------------------------------------------------------
// HH=4 aggregation, XCD-sliced + edge-fused + PARITY-SPLIT (round 15).
// R14 profile: FETCH 15MB (L2-resident slice confirmed) but VALUBusy 75% ->
// VALU-instruction-bound (~13 inst/edge for 2 FMAs). Now: 32 col-lanes x
// 4 cols (half4) x 2 edge-parities per wave -> addr calc + weight reads
// amortized over 2 edges x 4 cols; ~7.5 inst/edge. __shfl_xor(32) combines.
// ---------------------------------------------------------------------------
__global__ __launch_bounds__(64) void k_agg4s(
    const _Float16* __restrict__ h, const int* __restrict__ rowptr,
    const int* __restrict__ csr_src, const float* __restrict__ as_,
    const float* __restrict__ ad_, const float* __restrict__ Af,
    const float* __restrict__ Bf, _Float16* __restrict__ outh) {
  const int b = blockIdx.x;
  const int g = b & 7;            // column group -> XCD
  const int n = b >> 3;           // node
  const int lane = threadIdx.x;   // 0..63
  const int sub = lane >> 5;      // edge parity of this half-wave
  const int cl = lane & 31;
  const int c0 = g * 128 + cl * 4;
  const int head = g >> 1;
  __shared__ int s_src[64];
  __shared__ float s_al[64];
  const float adn = ad_[n * 4 + head];
  float a0 = 0.f, a1 = 0.f, a2 = 0.f, a3 = 0.f, wsum = 0.f;
  const int beg = rowptr[n], end = rowptr[n + 1];
  for (int base = beg; base < end; base += 64) {
    const int cnt = min(64, end - base);
    __syncthreads();
    if (lane < cnt) {
      const int s = csr_src[base + lane];
      s_src[lane] = s;
      float e = as_[s * 4 + head] + adn;
      e = e > 0.f ? e : 0.2f * e;
      s_al[lane] = expf(e);
    }
    __syncthreads();
    int j = sub;
    for (; j + 6 < cnt; j += 8) {  // 4 edges of this parity in flight
      float w[4];
      half4 v[4];
#pragma unroll
      for (int u = 0; u < 4; ++u) {
        const int jj = j + 2 * u;
        w[u] = s_al[jj];
        v[u] = *(const half4*)(h + (size_t)s_src[jj] * C1 + c0);
      }
#pragma unroll
      for (int u = 0; u < 4; ++u) {
        a0 += (float)v[u][0] * w[u];
        a1 += (float)v[u][1] * w[u];
        a2 += (float)v[u][2] * w[u];
        a3 += (float)v[u][3] * w[u];
        wsum += w[u];
      }
    }
    for (; j < cnt; j += 2) {
      const float w0 = s_al[j];
      const half4 v = *(const half4*)(h + (size_t)s_src[j] * C1 + c0);
      a0 += (float)v[0] * w0;
      a1 += (float)v[1] * w0;
      a2 += (float)v[2] * w0;
      a3 += (float)v[3] * w0;
      wsum += w0;
    }
  }
  // combine the two parities (lane i <-> lane i+32 hold same columns)
  a0 += __shfl_xor(a0, 32);
  a1 += __shfl_xor(a1, 32);
  a2 += __shfl_xor(a2, 32);
  a3 += __shfl_xor(a3, 32);
  wsum += __shfl_xor(wsum, 32);
  if (sub == 0) {
    const float idn = 1.f / (wsum + 1e-16f);
    float r[4] = {a0, a1, a2, a3};
    half4 ov;
#pragma unroll
    for (int i = 0; i < 4; ++i) {
      float val = r[i] * idn * Af[c0 + i] + Bf[c0 + i];
      val = val > 0.f ? val : expm1f(val);  // ELU
      ov[i] = (_Float16)val;
    }
    *(half4*)(outh + (size_t)n * C1 + c0) = ov;
  }
}

// ---------------------------------------------------------------------------
// HH=1 aggregation (layer 3), edge-fused + parity-split: 32 lanes x half8 x
// 2 parities. fp16 out (feeds fc12).
// ---------------------------------------------------------------------------
__global__ __launch_bounds__(64) void k_agg1(
    const _Float16* __restrict__ h, const int* __restrict__ rowptr,
    const int* __restrict__ csr_src, const float* __restrict__ as_,
    const float* __restrict__ ad_, const float* __restrict__ bias,
    _Float16* __restrict__ outh) {
  const int n = blockIdx.x;
  const int lane = threadIdx.x;
  const int sub = lane >> 5;
  const int cl = lane & 31;
  const int c0 = cl * 8;
  __shared__ int s_src[64];
  __shared__ float s_al[64];
  const float adn = ad_[n];
  float acc[8] = {};
  float wsum = 0.f;
  const int beg = rowptr[n], end = rowptr[n + 1];
  for (int base = beg; base < end; base += 64) {
    const int cnt = min(64, end - base);
    __syncthreads();
    if (lane < cnt) {
      const int s = csr_src[base + lane];
      s_src[lane] = s;
      float e = as_[s] + adn;
      e = e > 0.f ? e : 0.2f * e;
      s_al[lane] = expf(e);
    }
    __syncthreads();
    int j = sub;
    for (; j + 2 < cnt; j += 4) {  // 2 edges of this parity in flight
      float w[2];
      half8 v[2];
#pragma unroll
      for (int u = 0; u < 2; ++u) {
        const int jj = j + 2 * u;
        w[u] = s_al[jj];
        v[u] = *(const half8*)(h + (size_t)s_src[jj] * DH + c0);
      }
#pragma unroll
      for (int u = 0; u < 2; ++u) {
#pragma unroll
        for (int i = 0; i < 8; ++i) acc[i] += (float)v[u][i] * w[u];
        wsum += w[u];
      }
    }
    for (; j < cnt; j += 2) {
      const float w0 = s_al[j];
      const half8 v = *(const half8*)(h + (size_t)s_src[j] * DH + c0);
#pragma unroll
      for (int i = 0; i < 8; ++i) acc[i] += (float)v[i] * w0;
      wsum += w0;
    }
  }
#pragma unroll
  for (int i = 0; i < 8; ++i) acc[i] += __shfl_xor(acc[i], 32);
  wsum += __shfl_xor(wsum, 32);
  if (sub == 0) {
    const float idn = 1.f / (wsum + 1e-16f);
    half8 ov;
#pragma unroll
    for (int i = 0; i < 8; i++) {
      const int c = c0 + i;
      float val = acc[i] * idn + bias[c];
      val = val > 0.f ? val : expm1f(val);  // ELU
      ov[i] = (_Float16)val;
    }
    *(half8*)(outh + (size_t)n * DH + c0) = ov;
  }
}

// ---------------------------------------------------------------------------
extern "C" void kernel_launch(void* const* d_in, const int* in_sizes, int n_in,
                              void* d_out, int out_size, void* d_ws,
                              size_t ws_size, hipStream_t stream) {
  const float* x    = (const float*)d_in[0];
  const int*   ei   = (const int*)d_in[1];
  const float* W1   = (const float*)d_in[2];
  const float* a1s  = (const float*)d_in[3];
  const float* a1d  = (const float*)d_in[4];
  const float* b1   = (const float*)d_in[5];
  const float* W2   = (const float*)d_in[6];
  const float* a2s  = (const float*)d_in[7];
  const float* a2d  = (const float*)d_in[8];
  const float* b2   = (const float*)d_in[9];
  const float* W3   = (const float*)d_in[10];
  const float* a3s  = (const float*)d_in[11];
  const float* a3d  = (const float*)d_in[12];
  const float* b3   = (const float*)d_in[13];
  const float* g1   = (const float*)d_in[14];
  const float* be1  = (const float*)d_in[15];
  const float* m1   = (const float*)d_in[16];
  const float* v1   = (const float*)d_in[17];
  const float* g2   = (const float*)d_in[18];
  const float* be2  = (const float*)d_in[19];
  const float* m2   = (const float*)d_in[20];
  const float* v2   = (const float*)d_in[21];
  const float* fc1W = (const float*)d_in[22];
  const float* fc1b = (const float*)d_in[23];
  const float* fc2W = (const float*)d_in[24];
  const float* fc2b = (const float*)d_in[25];
  float* out = (float*)d_out;

  char* p = (char*)d_ws;
  auto alloc = [&](size_t bytes) -> void* {
    void* r = (void*)p;
    p += (bytes + 255) & ~(size_t)255;
    return r;
  };
  _Float16* hA     = (_Float16*)alloc((size_t)M_PAD * C1 * 2);  // GEMM in (holds xh)
  _Float16* hG     = (_Float16*)alloc((size_t)M_PAD * C1 * 2);  // GEMM out
  _Float16* w1h    = (_Float16*)alloc((size_t)C1 * K1PAD * 2);
  _Float16* w2h    = (_Float16*)alloc((size_t)C1 * C1 * 2);
  _Float16* w3h    = (_Float16*)alloc((size_t)DH * C1 * 2);
  _Float16* fwh    = (_Float16*)alloc((size_t)128 * DH * 2);
  _Float16* y16    = (_Float16*)alloc((size_t)M_PAD * DH * 2);  // agg3 out
  float*    as_    = (float*)alloc((size_t)N_NODES * HEADS * 4);
  float*    ad_    = (float*)alloc((size_t)N_NODES * HEADS * 4);
  float*    Afold  = (float*)alloc((size_t)2 * C1 * 4);
  float*    Bfold  = (float*)alloc((size_t)2 * C1 * 4);
  int*      rowptr = (int*)alloc((size_t)(N_NODES + 1) * 4);
  int*      csrS   = (int*)alloc((size_t)ETOT * 4);
  // single zero-block: cnt1[N] cnt2[N]
  const size_t ZN = (size_t)N_NODES * 2 * 4;  // 80 KB
  char*     zbuf   = (char*)alloc(ZN);
  int*      cnt1   = (int*)zbuf;
  int*      cnt2   = cnt1 + N_NODES;

  const int eb = (ETOT + 255) / 256;
  _Float16* xh = hA;  // alias: [M_PAD][K1PAD], gemm1 reads before agg1 writes

  // ---- one memset for both CSR counters ----
  hipMemsetAsync(zbuf, 0, ZN, stream);
  // ---- CSR build ----
  k_count<<<eb, 256, 0, stream>>>(ei, cnt1);
  k_scan<<<1, 256, 0, stream>>>(cnt1, rowptr);
  k_fill<<<eb, 256, 0, stream>>>(ei, rowptr, cnt2, csrS);
  // ---- all conversions + BN folds (input-only deps) ----
  k_cvt_all<<<(CV_TOT + 255) / 256, 256, 0, stream>>>(
      x, W1, W2, W3, fc1W, xh, w1h, w2h, w3h, fwh);
  k_bnp2<<<(2 * C1 + 255) / 256, 256, 0, stream>>>(
      b1, g1, be1, m1, v1, b2, g2, be2, m2, v2, Afold, Bfold);

  // ---- Layer 1: GATConv(300 -> 4x256) + BN1 + ELU ----
  k_mfma_gemm<<<dim3(C1 / 128, M_PAD / 128), 256, 0, stream>>>(
      xh, w1h, hG, N_NODES, C1, K1PAD);
  k_alpha<4><<<N_NODES, 256, 0, stream>>>(hG, a1s, a1d, as_, ad_);
  k_agg4s<<<N_NODES * 8, 64, 0, stream>>>(hG, rowptr, csrS, as_, ad_,
                                          Afold, Bfold, hA);

  // ---- Layer 2: GATConv(1024 -> 4x256) + BN2 + ELU ----
  k_mfma_gemm<<<dim3(C1 / 128, M_PAD / 128), 256, 0, stream>>>(
      hA, w2h, hG, N_NODES, C1, C1);
  k_alpha<4><<<N_NODES, 256, 0, stream>>>(hG, a2s, a2d, as_, ad_);
  k_agg4s<<<N_NODES * 8, 64, 0, stream>>>(hG, rowptr, csrS, as_, ad_,
                                          Afold + C1, Bfold + C1, hA);

  // ---- Layer 3: GATConv(1024 -> 256, heads=1) + ELU ----
  k_mfma_gemm<<<dim3(DH / 128, M_PAD / 128), 256, 0, stream>>>(
      hA, w3h, hG, N_NODES, DH, C1);
  k_alpha<1><<<N_NODES, 64, 0, stream>>>(hG, a3s, a3d, as_, ad_);
  k_agg1<<<N_NODES, 64, 0, stream>>>(hG, rowptr, csrS, as_, ad_, b3, y16);

  // ---- Fused MLP head: fc1 MFMA + in-block fc2 ----
  k_fc12<<<M_PAD / 128, 256, 0, stream>>>(y16, fwh, fc1b, fc2W, fc2b, out);
}